// Round 1
// baseline (1735.594 us; speedup 1.0000x reference)
//
#include <hip/hip_runtime.h>

typedef unsigned short ushort_t;
typedef unsigned int u32;
typedef short bf16x8 __attribute__((ext_vector_type(8)));
typedef float f32x4 __attribute__((ext_vector_type(4)));

__device__ __forceinline__ ushort_t f2bf(float f) {
  u32 u = __builtin_bit_cast(u32, f);
  u += 0x7FFFu + ((u >> 16) & 1u);   // round-to-nearest-even
  return (ushort_t)(u >> 16);
}
__device__ __forceinline__ float bf2f(u32 bits16) {
  return __builtin_bit_cast(float, bits16 << 16);
}

// ---------------- fp32 -> bf16 convert (8 elems/thread) ----------------
__global__ __launch_bounds__(256)
void cvt_kernel(const float* __restrict__ in, ushort_t* __restrict__ out) {
  const int i = blockIdx.x * 256 + threadIdx.x;   // 0 .. 2097151 (16M elems / 8)
  const float4 a = ((const float4*)in)[(size_t)i * 2];
  const float4 b = ((const float4*)in)[(size_t)i * 2 + 1];
  uint4 r;
  r.x = (u32)f2bf(a.x) | ((u32)f2bf(a.y) << 16);
  r.y = (u32)f2bf(a.z) | ((u32)f2bf(a.w) << 16);
  r.z = (u32)f2bf(b.x) | ((u32)f2bf(b.y) << 16);
  r.w = (u32)f2bf(b.z) | ((u32)f2bf(b.w) << 16);
  ((uint4*)out)[i] = r;
}

// ---------------- GEMM: C[m][n] = sum_k A[m][k] * B[n][k]  (B^T input) ----------------
// 128x128 tile, BK=64, 4 waves, 16x16x32 bf16 MFMA, global_load_lds width 16.
template <int F32OUT>
__global__ __launch_bounds__(256)
void gemm_bt(const ushort_t* __restrict__ A, const ushort_t* __restrict__ B,
             void* __restrict__ C) {
  constexpr int Kdim = 4096, Ndim = 4096;
  __shared__ ushort_t sA[128 * 64];
  __shared__ ushort_t sB[128 * 64];
  const int tid = threadIdx.x, lane = tid & 63, wave = tid >> 6;
  const int lq = lane & 15, g = lane >> 4;
  const int bm = blockIdx.x * 128, bn = blockIdx.y * 128;
  const int wr = (wave >> 1) * 64, wc = (wave & 1) * 64;
  const int srow = lane >> 3, scol = (lane & 7) * 8;  // staging: 8 rows x 64 cols per wave-call
  f32x4 acc[4][4];
#pragma unroll
  for (int m = 0; m < 4; ++m)
#pragma unroll
    for (int n = 0; n < 4; ++n) acc[m][n] = (f32x4)0.f;

  for (int kt = 0; kt < Kdim; kt += 64) {
#pragma unroll
    for (int c = 0; c < 4; ++c) {
      const int r0 = (c * 4 + wave) * 8 + srow;
      const ushort_t* ga = A + (size_t)(bm + r0) * Kdim + kt + scol;
      const ushort_t* gb = B + (size_t)(bn + r0) * Kdim + kt + scol;
      __builtin_amdgcn_global_load_lds(
          (const __attribute__((address_space(1))) u32*)ga,
          (__attribute__((address_space(3))) u32*)&sA[r0 * 64 + scol], 16, 0, 0);
      __builtin_amdgcn_global_load_lds(
          (const __attribute__((address_space(1))) u32*)gb,
          (__attribute__((address_space(3))) u32*)&sB[r0 * 64 + scol], 16, 0, 0);
    }
    __syncthreads();
#pragma unroll
    for (int kk = 0; kk < 2; ++kk) {
      bf16x8 af[4], bfr[4];
#pragma unroll
      for (int m = 0; m < 4; ++m)
        af[m] = *(const bf16x8*)&sA[(wr + m * 16 + lq) * 64 + kk * 32 + g * 8];
#pragma unroll
      for (int n = 0; n < 4; ++n)
        bfr[n] = *(const bf16x8*)&sB[(wc + n * 16 + lq) * 64 + kk * 32 + g * 8];
#pragma unroll
      for (int m = 0; m < 4; ++m)
#pragma unroll
        for (int n = 0; n < 4; ++n)
          acc[m][n] = __builtin_amdgcn_mfma_f32_16x16x32_bf16(af[m], bfr[n], acc[m][n], 0, 0, 0);
    }
    __syncthreads();
  }
  // C/D layout: col = lane&15, row = (lane>>4)*4 + reg
#pragma unroll
  for (int m = 0; m < 4; ++m)
#pragma unroll
    for (int r = 0; r < 4; ++r) {
      const int row = bm + wr + m * 16 + g * 4 + r;
#pragma unroll
      for (int n = 0; n < 4; ++n) {
        const int col = bn + wc + n * 16 + lq;
        if (F32OUT)
          ((float*)C)[(size_t)row * Ndim + col] = acc[m][n][r];
        else
          ((ushort_t*)C)[(size_t)row * Ndim + col] = f2bf(acc[m][n][r]);
      }
    }
}

// ---------------- RoPE (in-place on bf16 Q and K); Q also gets 1/sqrt(128) ----------------
__global__ __launch_bounds__(256)
void rope_kernel(ushort_t* __restrict__ Q, ushort_t* __restrict__ K,
                 const float* __restrict__ fcos, const float* __restrict__ fsin) {
  const int gid = blockIdx.x * 256 + threadIdx.x;  // 2^21 per tensor
  ushort_t* T = blockIdx.y ? K : Q;
  const float scale = blockIdx.y ? 1.f : 0.08838834764831845f;
  const int j8 = gid & 15;
  const int h = (gid >> 4) & 31;
  const int s = (gid >> 9) & 2047;
  const int b = gid >> 20;
  const size_t off = (size_t)(b * 2048 + s) * 4096 + h * 128 + j8 * 8;
  uint4 v = *(const uint4*)(T + off);
  const float4 c4 = *(const float4*)(fcos + s * 64 + j8 * 4);
  const float4 s4 = *(const float4*)(fsin + s * 64 + j8 * 4);
  u32 w[4] = {v.x, v.y, v.z, v.w};
  const float cc[4] = {c4.x, c4.y, c4.z, c4.w};
  const float ss[4] = {s4.x, s4.y, s4.z, s4.w};
#pragma unroll
  for (int p = 0; p < 4; ++p) {
    const float t0 = bf2f(w[p] & 0xffffu);
    const float t1 = bf2f(w[p] >> 16);
    const float r0 = (t0 * cc[p] - t1 * ss[p]) * scale;
    const float r1 = (t0 * ss[p] + t1 * cc[p]) * scale;
    w[p] = (u32)f2bf(r0) | ((u32)f2bf(r1) << 16);
  }
  v.x = w[0]; v.y = w[1]; v.z = w[2]; v.w = w[3];
  *(uint4*)(T + off) = v;
}

// ---------------- Flash attention, causal ----------------
// 1 wave = 16 q rows. Swapped QK^T: S^T = mfma(A=K_tile, B=Q), so softmax
// reduction over keys is reg-wise + shfl_xor(16/32). P moved to A-layout via
// 16 shuffles, PV B-operand from pre-transposed V^T (contiguous 16B loads).
__global__ __launch_bounds__(256)
void attn_kernel(const ushort_t* __restrict__ Q, const ushort_t* __restrict__ K,
                 const ushort_t* __restrict__ Vt, ushort_t* __restrict__ O) {
  const int lane = threadIdx.x & 63;
  const int wave = threadIdx.x >> 6;
  const int t = blockIdx.x * 4 + wave;  // 0..8191
  const int qt = t & 127, bh = t >> 7;
  const int h = bh & 31, b = bh >> 5;
  const int qbase = qt * 16;
  const int lq = lane & 15, g = lane >> 4;

  bf16x8 aq[4];
  const size_t qoff = (size_t)(b * 2048 + qbase + lq) * 4096 + h * 128 + g * 8;
#pragma unroll
  for (int kf = 0; kf < 4; ++kf) aq[kf] = *(const bf16x8*)(Q + qoff + kf * 32);

  f32x4 o[8];
#pragma unroll
  for (int dt = 0; dt < 8; ++dt) o[dt] = (f32x4)0.f;
  float m_run = -1e30f, l_run = 0.f;
  const int nt = (qbase + 47) >> 5;
  const size_t krowbase = (size_t)(b * 2048) * 4096 + h * 128 + g * 8;
  const size_t vbase = (size_t)(h * 128 + lq) * 4096 + b * 2048 + g * 8;

  for (int kt = 0; kt < nt; ++kt) {
    const int kb = kt * 32;
    f32x4 st0 = (f32x4)0.f, st1 = (f32x4)0.f;
#pragma unroll
    for (int kf = 0; kf < 4; ++kf) {
      bf16x8 ak0 = *(const bf16x8*)(K + krowbase + (size_t)(kb + lq) * 4096 + kf * 32);
      bf16x8 ak1 = *(const bf16x8*)(K + krowbase + (size_t)(kb + 16 + lq) * 4096 + kf * 32);
      st0 = __builtin_amdgcn_mfma_f32_16x16x32_bf16(ak0, aq[kf], st0, 0, 0, 0);
      st1 = __builtin_amdgcn_mfma_f32_16x16x32_bf16(ak1, aq[kf], st1, 0, 0, 0);
    }
    // S^T layout: col(lane&15)=q, row=(lane>>4)*4+reg = key_local
    float sv[8];
#pragma unroll
    for (int r = 0; r < 4; ++r) { sv[r] = st0[r]; sv[4 + r] = st1[r]; }
    if (kb + 31 > qbase) {
      const int q = qbase + lq;
#pragma unroll
      for (int i = 0; i < 8; ++i) {
        const int key = kb + (i >> 2) * 16 + g * 4 + (i & 3);
        if (key > q) sv[i] = -1e30f;
      }
    }
    float tm = sv[0];
#pragma unroll
    for (int i = 1; i < 8; ++i) tm = fmaxf(tm, sv[i]);
    tm = fmaxf(tm, __shfl_xor(tm, 16));
    tm = fmaxf(tm, __shfl_xor(tm, 32));
    const float m_new = fmaxf(m_run, tm);
    const float corr = __expf(m_run - m_new);
    float p[8], rs = 0.f;
#pragma unroll
    for (int i = 0; i < 8; ++i) { p[i] = __expf(sv[i] - m_new); rs += p[i]; }
    rs += __shfl_xor(rs, 16);
    rs += __shfl_xor(rs, 32);
    l_run = l_run * corr + rs;
    m_run = m_new;
    // O rescale: O row = g*4+r; factor lives in lane (g*4+r) (its lane&15 == q)
    float fr[4];
#pragma unroll
    for (int r = 0; r < 4; ++r) fr[r] = __shfl(corr, g * 4 + r);
#pragma unroll
    for (int dt = 0; dt < 8; ++dt)
#pragma unroll
      for (int r = 0; r < 4; ++r) o[dt][r] *= fr[r];
    // Transpose P (C-layout of S^T) -> A-layout frag: lane holds q=lane&15, keys g*8+j
    bf16x8 pa;
#pragma unroll
    for (int j = 0; j < 8; ++j) {
      const int src = lq + 16 * (2 * (g & 1) + (j >> 2));
      const float v0 = __shfl(p[j & 3], src);       // from st0 (keys 0..15)
      const float v1 = __shfl(p[4 + (j & 3)], src); // from st1 (keys 16..31)
      pa[j] = (short)f2bf(g < 2 ? v0 : v1);
    }
    // PV: O[dt] += P(16x32) @ V(32x16); V^T rows are s-contiguous
#pragma unroll
    for (int dt = 0; dt < 8; ++dt) {
      bf16x8 vf = *(const bf16x8*)(Vt + vbase + (size_t)(dt * 16) * 4096 + kb);
      o[dt] = __builtin_amdgcn_mfma_f32_16x16x32_bf16(pa, vf, o[dt], 0, 0, 0);
    }
  }
  const float inv = 1.f / l_run;
  float linv[4];
#pragma unroll
  for (int r = 0; r < 4; ++r) linv[r] = __shfl(inv, g * 4 + r);
  const size_t obase = (size_t)(b * 2048 + qbase) * 4096 + h * 128 + lq;
#pragma unroll
  for (int dt = 0; dt < 8; ++dt)
#pragma unroll
    for (int r = 0; r < 4; ++r)
      O[obase + (size_t)(g * 4 + r) * 4096 + dt * 16] = f2bf(o[dt][r] * linv[r]);
}

// ---------------- host ----------------
extern "C" void kernel_launch(void* const* d_in, const int* in_sizes, int n_in,
                              void* d_out, int out_size, void* d_ws, size_t ws_size,
                              hipStream_t stream) {
  const float* x = (const float*)d_in[0];
  const float* fcos = (const float*)d_in[2];
  const float* fsin = (const float*)d_in[3];
  const float* wq = (const float*)d_in[5];
  const float* wk = (const float*)d_in[6];
  const float* wv = (const float*)d_in[7];
  const float* wo = (const float*)d_in[8];
  float* out = (float*)d_out;
  char* ws = (char*)d_ws;
  const size_t MB32 = 33554432;  // 4096*4096*2 bytes
  ushort_t* xb = (ushort_t*)(ws);
  ushort_t* wb = (ushort_t*)(ws + MB32);
  ushort_t* Qb = (ushort_t*)(ws + 2 * MB32);
  ushort_t* Kb = (ushort_t*)(ws + 3 * MB32);
  ushort_t* Vt = (ushort_t*)(ws + 4 * MB32);
  ushort_t* Ob = xb;  // reuse: x no longer needed after V^T gemm

  const dim3 cb(256);
  const dim3 cg(8192);
  const dim3 gg(32, 32);

  hipLaunchKernelGGL(cvt_kernel, cg, cb, 0, stream, x, xb);
  hipLaunchKernelGGL(cvt_kernel, cg, cb, 0, stream, wq, wb);
  hipLaunchKernelGGL((gemm_bt<0>), gg, cb, 0, stream, xb, wb, (void*)Qb);
  hipLaunchKernelGGL(cvt_kernel, cg, cb, 0, stream, wk, wb);
  hipLaunchKernelGGL((gemm_bt<0>), gg, cb, 0, stream, xb, wb, (void*)Kb);
  hipLaunchKernelGGL(cvt_kernel, cg, cb, 0, stream, wv, wb);
  hipLaunchKernelGGL((gemm_bt<0>), gg, cb, 0, stream, wb, xb, (void*)Vt);  // V^T = Wv @ x^T
  hipLaunchKernelGGL(rope_kernel, dim3(8192, 2), cb, 0, stream, Qb, Kb, fcos, fsin);
  hipLaunchKernelGGL(attn_kernel, dim3(2048), cb, 0, stream, Qb, Kb, Vt, Ob);
  hipLaunchKernelGGL(cvt_kernel, cg, cb, 0, stream, wo, wb);
  hipLaunchKernelGGL((gemm_bt<1>), gg, cb, 0, stream, Ob, wb, (void*)out);
}

// Round 2
// 949.138 us; speedup vs baseline: 1.8286x; 1.8286x over previous
//
#include <hip/hip_runtime.h>

typedef unsigned short ushort_t;
typedef unsigned int u32;
typedef short bf16x8 __attribute__((ext_vector_type(8)));
typedef float f32x4 __attribute__((ext_vector_type(4)));
typedef float f32x16 __attribute__((ext_vector_type(16)));
typedef u32 u32x4 __attribute__((ext_vector_type(4)));

__device__ __forceinline__ ushort_t f2bf(float f) {
  u32 u = __builtin_bit_cast(u32, f);
  u += 0x7FFFu + ((u >> 16) & 1u);   // round-to-nearest-even
  return (ushort_t)(u >> 16);
}
__device__ __forceinline__ float bf2f(u32 bits16) {
  return __builtin_bit_cast(float, bits16 << 16);
}

// ---------------- fp32 -> bf16 convert (8 elems/thread) ----------------
__global__ __launch_bounds__(256)
void cvt_kernel(const float* __restrict__ in, ushort_t* __restrict__ out) {
  const int i = blockIdx.x * 256 + threadIdx.x;
  const float4 a = ((const float4*)in)[(size_t)i * 2];
  const float4 b = ((const float4*)in)[(size_t)i * 2 + 1];
  uint4 r;
  r.x = (u32)f2bf(a.x) | ((u32)f2bf(a.y) << 16);
  r.y = (u32)f2bf(a.z) | ((u32)f2bf(a.w) << 16);
  r.z = (u32)f2bf(b.x) | ((u32)f2bf(b.y) << 16);
  r.w = (u32)f2bf(b.z) | ((u32)f2bf(b.w) << 16);
  ((uint4*)out)[i] = r;
}

// ---------------- GEMM: C[m][n] = sum_k A[m][k] * B[n][k]  (B^T input) ----------------
template <int F32OUT>
__global__ __launch_bounds__(256)
void gemm_bt(const ushort_t* __restrict__ A, const ushort_t* __restrict__ B,
             void* __restrict__ C) {
  constexpr int Kdim = 4096, Ndim = 4096;
  __shared__ ushort_t sA[128 * 64];
  __shared__ ushort_t sB[128 * 64];
  const int tid = threadIdx.x, lane = tid & 63, wave = tid >> 6;
  const int lq = lane & 15, g = lane >> 4;
  const int bm = blockIdx.x * 128, bn = blockIdx.y * 128;
  const int wr = (wave >> 1) * 64, wc = (wave & 1) * 64;
  const int srow = lane >> 3, scol = (lane & 7) * 8;
  f32x4 acc[4][4];
#pragma unroll
  for (int m = 0; m < 4; ++m)
#pragma unroll
    for (int n = 0; n < 4; ++n) acc[m][n] = (f32x4)0.f;

  for (int kt = 0; kt < Kdim; kt += 64) {
#pragma unroll
    for (int c = 0; c < 4; ++c) {
      const int r0 = (c * 4 + wave) * 8 + srow;
      const ushort_t* ga = A + (size_t)(bm + r0) * Kdim + kt + scol;
      const ushort_t* gb = B + (size_t)(bn + r0) * Kdim + kt + scol;
      __builtin_amdgcn_global_load_lds(
          (const __attribute__((address_space(1))) u32*)ga,
          (__attribute__((address_space(3))) u32*)&sA[r0 * 64 + scol], 16, 0, 0);
      __builtin_amdgcn_global_load_lds(
          (const __attribute__((address_space(1))) u32*)gb,
          (__attribute__((address_space(3))) u32*)&sB[r0 * 64 + scol], 16, 0, 0);
    }
    __syncthreads();
#pragma unroll
    for (int kk = 0; kk < 2; ++kk) {
      bf16x8 af[4], bfr[4];
#pragma unroll
      for (int m = 0; m < 4; ++m)
        af[m] = *(const bf16x8*)&sA[(wr + m * 16 + lq) * 64 + kk * 32 + g * 8];
#pragma unroll
      for (int n = 0; n < 4; ++n)
        bfr[n] = *(const bf16x8*)&sB[(wc + n * 16 + lq) * 64 + kk * 32 + g * 8];
#pragma unroll
      for (int m = 0; m < 4; ++m)
#pragma unroll
        for (int n = 0; n < 4; ++n)
          acc[m][n] = __builtin_amdgcn_mfma_f32_16x16x32_bf16(af[m], bfr[n], acc[m][n], 0, 0, 0);
    }
    __syncthreads();
  }
#pragma unroll
  for (int m = 0; m < 4; ++m)
#pragma unroll
    for (int r = 0; r < 4; ++r) {
      const int row = bm + wr + m * 16 + g * 4 + r;
#pragma unroll
      for (int n = 0; n < 4; ++n) {
        const int col = bn + wc + n * 16 + lq;
        if (F32OUT)
          ((float*)C)[(size_t)row * Ndim + col] = acc[m][n][r];
        else
          ((ushort_t*)C)[(size_t)row * Ndim + col] = f2bf(acc[m][n][r]);
      }
    }
}

// ---------------- RoPE (in-place on bf16 Q and K); Q also gets 1/sqrt(128) ----------------
__global__ __launch_bounds__(256)
void rope_kernel(ushort_t* __restrict__ Q, ushort_t* __restrict__ K,
                 const float* __restrict__ fcos, const float* __restrict__ fsin) {
  const int gid = blockIdx.x * 256 + threadIdx.x;
  ushort_t* T = blockIdx.y ? K : Q;
  const float scale = blockIdx.y ? 1.f : 0.08838834764831845f;
  const int j8 = gid & 15;
  const int h = (gid >> 4) & 31;
  const int s = (gid >> 9) & 2047;
  const int b = gid >> 20;
  const size_t off = (size_t)(b * 2048 + s) * 4096 + h * 128 + j8 * 8;
  uint4 v = *(const uint4*)(T + off);
  const float4 c4 = *(const float4*)(fcos + s * 64 + j8 * 4);
  const float4 s4 = *(const float4*)(fsin + s * 64 + j8 * 4);
  u32 w[4] = {v.x, v.y, v.z, v.w};
  const float cc[4] = {c4.x, c4.y, c4.z, c4.w};
  const float ss[4] = {s4.x, s4.y, s4.z, s4.w};
#pragma unroll
  for (int p = 0; p < 4; ++p) {
    const float t0 = bf2f(w[p] & 0xffffu);
    const float t1 = bf2f(w[p] >> 16);
    const float r0 = (t0 * cc[p] - t1 * ss[p]) * scale;
    const float r1 = (t0 * ss[p] + t1 * cc[p]) * scale;
    w[p] = (u32)f2bf(r0) | ((u32)f2bf(r1) << 16);
  }
  v.x = w[0]; v.y = w[1]; v.z = w[2]; v.w = w[3];
  *(uint4*)(T + off) = v;
}

// ---------------- Flash attention, causal, 32x32 MFMA, folded-balance ----------------
// Block = 4 waves x 32 q-rows = 128 q-rows; block j does q-blocks {j, 15-j}
// (uniform 68 KV-tiles per block). K/V^T staged in LDS (2-phase double buffer,
// XOR-swizzled both-sides per rule #21). Swapped QK^T (S^T = K·Q^T) so softmax
// is in-register + 1 shfl_xor(32); P -> A-frag via cvt_pk_bf16 + permlane32_swap
// (T12); defer-max rescale (T13, THR=8).
__global__ __launch_bounds__(256, 2)
void attn_kernel(const ushort_t* __restrict__ Q, const ushort_t* __restrict__ K,
                 const ushort_t* __restrict__ Vt, ushort_t* __restrict__ O) {
  __shared__ ushort_t sK[2][32 * 128];   // 8KB per buf, swizzled col16 ^= row&7
  __shared__ ushort_t sV[2][128 * 32];   // 8KB per buf, swizzled slot ^= (d>>1)&3
  __shared__ float sScr[4][32];

  const int lane = threadIdx.x & 63, wave = threadIdx.x >> 6;
  const int lq = lane & 31, hi = lane >> 5;
  const int bp = blockIdx.x;
  const int bh = bp >> 3, j = bp & 7;
  const int h = bh & 31, b = bh >> 5;
  const ushort_t* Kb_ = K + (size_t)(b * 2048) * 4096 + h * 128;
  const ushort_t* Vb_ = Vt + (size_t)(h * 128) * 4096 + b * 2048;

#define STAGE(buf, kt_)                                                              \
  {                                                                                  \
    const int kb_ = (kt_) * 32;                                                      \
    _Pragma("unroll")                                                                \
    for (int i_ = 0; i_ < 2; ++i_) {                                                 \
      const int c_ = wave + i_ * 4;                                                  \
      const int krow = c_ * 4 + (lane >> 4);                                         \
      const int kcol = (lane & 15) ^ (krow & 7);                                     \
      const ushort_t* ksrc = Kb_ + (size_t)(kb_ + krow) * 4096 + kcol * 8;           \
      __builtin_amdgcn_global_load_lds(                                              \
          (const __attribute__((address_space(1))) u32*)ksrc,                        \
          (__attribute__((address_space(3))) u32*)&sK[buf][c_ * 512 + lane * 8],     \
          16, 0, 0);                                                                 \
      const int sst = c_ * 64 + lane;                                                \
      const int dv = sst >> 2;                                                       \
      const int gl = (sst & 3) ^ ((sst >> 3) & 3);                                   \
      const ushort_t* vsrc = Vb_ + (size_t)dv * 4096 + kb_ + gl * 8;                 \
      __builtin_amdgcn_global_load_lds(                                              \
          (const __attribute__((address_space(1))) u32*)vsrc,                        \
          (__attribute__((address_space(3))) u32*)&sV[buf][sst * 8], 16, 0, 0);      \
    }                                                                                \
  }

  for (int ph = 0; ph < 2; ++ph) {
    const int qj = ph ? (15 - j) : j;
    const int qbase = qj * 128 + wave * 32;
    const int ntw = qj * 4 + wave + 1;   // tiles this wave computes
    const int ntmax = qj * 4 + 4;        // tiles the block stages

    // Q B-fragments: lane holds Q[qbase+lq][kf*16 + hi*8 .. +8]
    bf16x8 aq[8];
    const ushort_t* qrow = Q + (size_t)(b * 2048 + qbase + lq) * 4096 + h * 128 + hi * 8;
#pragma unroll
    for (int kf = 0; kf < 8; ++kf) aq[kf] = *(const bf16x8*)(qrow + kf * 16);

    f32x16 o[4];
#pragma unroll
    for (int dt = 0; dt < 4; ++dt) o[dt] = (f32x16)0.f;
    float m_run = -1e30f, l_run = 0.f;

    int cur = 0;
    STAGE(0, 0);
    __syncthreads();

    for (int kt = 0; kt < ntmax; ++kt) {
      if (kt + 1 < ntmax) STAGE(cur ^ 1, kt + 1);
      if (kt < ntw) {
        const int kb = kt * 32;
        // ---- QK^T: S^T[key][q], key = crow(r,hi), q = lq ----
        f32x16 st = (f32x16)0.f;
#pragma unroll
        for (int kf = 0; kf < 8; ++kf) {
          const bf16x8 kfrag =
              *(const bf16x8*)&sK[cur][lq * 128 + (((kf * 2 + hi) ^ (lq & 7)) * 8)];
          st = __builtin_amdgcn_mfma_f32_32x32x16_bf16(kfrag, aq[kf], st, 0, 0, 0);
        }
        // causal mask — only the diagonal tile
        if (kt == ntw - 1) {
          const int q = qbase + lq;
#pragma unroll
          for (int r = 0; r < 16; ++r) {
            const int key = kb + (r & 3) + 8 * (r >> 2) + 4 * hi;
            if (key > q) st[r] = -1e30f;
          }
        }
        // ---- online softmax (q = lq lanewise; halves hold different keys) ----
        float tm = st[0];
#pragma unroll
        for (int r = 1; r < 16; ++r) tm = fmaxf(tm, st[r]);
        tm = fmaxf(tm, __shfl_xor(tm, 32));
        if (!__all(tm <= m_run + 8.f)) {   // T13 defer-max
          const float mnew = fmaxf(m_run, tm);
          const float corr = __expf(m_run - mnew);
          m_run = mnew;
          l_run *= corr;
          if (hi == 0) sScr[wave][lq] = corr;
          float fr[16];
#pragma unroll
          for (int r = 0; r < 16; ++r)
            fr[r] = sScr[wave][(r & 3) + 8 * (r >> 2) + 4 * hi];
#pragma unroll
          for (int dt = 0; dt < 4; ++dt)
#pragma unroll
            for (int r = 0; r < 16; ++r) o[dt][r] *= fr[r];
        }
        float rs = 0.f;
#pragma unroll
        for (int r = 0; r < 16; ++r) { st[r] = __expf(st[r] - m_run); rs += st[r]; }
        rs += __shfl_xor(rs, 32);
        l_run += rs;
        // ---- P -> bf16 A-fragments (8 cvt_pk + 4 permlane32_swap) ----
        u32 A_, B_, C_, D_, E_, F_, G_, H_;
#define CVTPK(d_, l_, h_) \
  asm("v_cvt_pk_bf16_f32 %0, %1, %2" : "=v"(d_) : "v"(l_), "v"(h_))
        CVTPK(A_, st[0], st[1]);  CVTPK(B_, st[4], st[5]);
        CVTPK(C_, st[2], st[3]);  CVTPK(D_, st[6], st[7]);
        CVTPK(E_, st[8], st[9]);  CVTPK(F_, st[12], st[13]);
        CVTPK(G_, st[10], st[11]); CVTPK(H_, st[14], st[15]);
#undef CVTPK
        asm volatile("v_permlane32_swap_b32 %0, %1" : "+v"(A_), "+v"(B_));
        asm volatile("v_permlane32_swap_b32 %0, %1" : "+v"(C_), "+v"(D_));
        asm volatile("v_permlane32_swap_b32 %0, %1" : "+v"(E_), "+v"(F_));
        asm volatile("v_permlane32_swap_b32 %0, %1" : "+v"(G_), "+v"(H_));
        const bf16x8 pa0 = __builtin_bit_cast(bf16x8, (u32x4){A_, C_, B_, D_});
        const bf16x8 pa1 = __builtin_bit_cast(bf16x8, (u32x4){E_, G_, F_, H_});
        // ---- PV: O[q][d] += P · V, V from swizzled V^T tile ----
#pragma unroll
        for (int dt = 0; dt < 4; ++dt) {
          const int d0 = dt * 32 + lq;
          const int s0 = 4 * d0 + ((hi + 0) ^ ((d0 >> 1) & 3));
          const int s1 = 4 * d0 + ((hi + 2) ^ ((d0 >> 1) & 3));
          const bf16x8 vf0 = *(const bf16x8*)&sV[cur][s0 * 8];
          const bf16x8 vf1 = *(const bf16x8*)&sV[cur][s1 * 8];
          o[dt] = __builtin_amdgcn_mfma_f32_32x32x16_bf16(pa0, vf0, o[dt], 0, 0, 0);
          o[dt] = __builtin_amdgcn_mfma_f32_32x32x16_bf16(pa1, vf1, o[dt], 0, 0, 0);
        }
      }
      __syncthreads();
      cur ^= 1;
    }

    // ---- epilogue: normalize by 1/l (broadcast via LDS), store O ----
    if (hi == 0) sScr[wave][lq] = 1.f / l_run;
    __syncthreads();
    const size_t obase = (size_t)(b * 2048 + qbase) * 4096 + h * 128;
#pragma unroll
    for (int r = 0; r < 16; ++r) {
      const int qr = (r & 3) + 8 * (r >> 2) + 4 * hi;
      const float f = sScr[wave][qr];
#pragma unroll
      for (int dt = 0; dt < 4; ++dt)
        O[obase + (size_t)qr * 4096 + dt * 32 + lq] = f2bf(o[dt][r] * f);
    }
    __syncthreads();
  }
#undef STAGE
}

// ---------------- host ----------------
extern "C" void kernel_launch(void* const* d_in, const int* in_sizes, int n_in,
                              void* d_out, int out_size, void* d_ws, size_t ws_size,
                              hipStream_t stream) {
  const float* x = (const float*)d_in[0];
  const float* fcos = (const float*)d_in[2];
  const float* fsin = (const float*)d_in[3];
  const float* wq = (const float*)d_in[5];
  const float* wk = (const float*)d_in[6];
  const float* wv = (const float*)d_in[7];
  const float* wo = (const float*)d_in[8];
  float* out = (float*)d_out;
  char* ws = (char*)d_ws;
  const size_t MB32 = 33554432;  // 4096*4096*2 bytes
  ushort_t* xb = (ushort_t*)(ws);
  ushort_t* wb = (ushort_t*)(ws + MB32);
  ushort_t* Qb = (ushort_t*)(ws + 2 * MB32);
  ushort_t* Kb = (ushort_t*)(ws + 3 * MB32);
  ushort_t* Vt = (ushort_t*)(ws + 4 * MB32);
  ushort_t* Ob = xb;  // reuse: x no longer needed after V^T gemm

  const dim3 cb(256);
  const dim3 cg(8192);
  const dim3 gg(32, 32);

  hipLaunchKernelGGL(cvt_kernel, cg, cb, 0, stream, x, xb);
  hipLaunchKernelGGL(cvt_kernel, cg, cb, 0, stream, wq, wb);
  hipLaunchKernelGGL((gemm_bt<0>), gg, cb, 0, stream, xb, wb, (void*)Qb);
  hipLaunchKernelGGL(cvt_kernel, cg, cb, 0, stream, wk, wb);
  hipLaunchKernelGGL((gemm_bt<0>), gg, cb, 0, stream, xb, wb, (void*)Kb);
  hipLaunchKernelGGL(cvt_kernel, cg, cb, 0, stream, wv, wb);
  hipLaunchKernelGGL((gemm_bt<0>), gg, cb, 0, stream, wb, xb, (void*)Vt);  // V^T = Wv @ x^T
  hipLaunchKernelGGL(rope_kernel, dim3(8192, 2), cb, 0, stream, Qb, Kb, fcos, fsin);
  hipLaunchKernelGGL(attn_kernel, dim3(512), cb, 0, stream, Qb, Kb, Vt, Ob);
  hipLaunchKernelGGL(cvt_kernel, cg, cb, 0, stream, wo, wb);
  hipLaunchKernelGGL((gemm_bt<1>), gg, cb, 0, stream, Ob, wb, (void*)out);
}

// Round 3
// 680.335 us; speedup vs baseline: 2.5511x; 1.3951x over previous
//
#include <hip/hip_runtime.h>

typedef unsigned short ushort_t;
typedef unsigned int u32;
typedef short bf16x8 __attribute__((ext_vector_type(8)));
typedef float f32x4 __attribute__((ext_vector_type(4)));
typedef float f32x16 __attribute__((ext_vector_type(16)));
typedef u32 u32x4 __attribute__((ext_vector_type(4)));

__device__ __forceinline__ ushort_t f2bf(float f) {
  u32 u = __builtin_bit_cast(u32, f);
  u += 0x7FFFu + ((u >> 16) & 1u);   // round-to-nearest-even
  return (ushort_t)(u >> 16);
}
__device__ __forceinline__ float bf2f(u32 bits16) {
  return __builtin_bit_cast(float, bits16 << 16);
}

// ---------------- fp32 -> bf16 convert (8 elems/thread) ----------------
__global__ __launch_bounds__(256)
void cvt_kernel(const float* __restrict__ in, ushort_t* __restrict__ out) {
  const int i = blockIdx.x * 256 + threadIdx.x;
  const float4 a = ((const float4*)in)[(size_t)i * 2];
  const float4 b = ((const float4*)in)[(size_t)i * 2 + 1];
  uint4 r;
  r.x = (u32)f2bf(a.x) | ((u32)f2bf(a.y) << 16);
  r.y = (u32)f2bf(a.z) | ((u32)f2bf(a.w) << 16);
  r.z = (u32)f2bf(b.x) | ((u32)f2bf(b.y) << 16);
  r.w = (u32)f2bf(b.z) | ((u32)f2bf(b.w) << 16);
  ((uint4*)out)[i] = r;
}

// ---------------- GEMM 256x256 8-phase: C[m][n] = sum_k A[m][k]*B[n][k] ----------------
// 512 threads = 8 waves (2M x 4N), BK=64, 64 K-tiles. LDS: per tensor 2 slots x
// 2 halves x (128x64) bf16 = 64 KiB -> 128 KiB total. T2 chunk^=(row&7) swizzle
// (inverse-swizzled global source, linear LDS dest, swizzled ds_read). Per K-tile
// 4 phases (Gray quadrant walk), counted vmcnt(6) once per tile (T4), setprio
// around MFMA clusters (T5), raw s_barrier (no compiler vmcnt-drain).
template <int F32OUT>
__global__ __launch_bounds__(512, 2)
void gemm256(const ushort_t* __restrict__ A, const ushort_t* __restrict__ B,
             void* __restrict__ C) {
  constexpr int KD = 4096, ND = 4096;
  __shared__ ushort_t sA[2][2][128 * 64];
  __shared__ ushort_t sB[2][2][128 * 64];
  const int tid = threadIdx.x;
  const int lane = tid & 63, wave = tid >> 6;
  const int lq = lane & 15, g = lane >> 4;
  const int wm = wave >> 2, wn = wave & 3;
  const int id = blockIdx.x;
  const int swz = (id & 7) * 32 + (id >> 3);       // bijective XCD swizzle (256%8==0)
  const int bm = (swz >> 4) * 256;
  const int bn = (swz & 15) * 256;
  const int csw = ((lane & 7) ^ (lane >> 3)) * 8;  // inverse-swizzled source chunk
  const int srow = lane >> 3;

  f32x4 acc[8][4];
#pragma unroll
  for (int m = 0; m < 8; ++m)
#pragma unroll
    for (int n = 0; n < 4; ++n) acc[m][n] = (f32x4)0.f;

// stage one half-tile (128x64) of tensor G (K-tile t_, slot s_, half h_);
// 2 global_load_lds x 8 rows per wave; LDS dest linear, source pre-swizzled.
#define STG(sbuf, G, rowb, t_, s_, h_)                                               \
  {                                                                                  \
    _Pragma("unroll") for (int i_ = 0; i_ < 2; ++i_) {                               \
      const int r0_ = wave * 16 + i_ * 8;                                            \
      const int tc_ = (t_) > 63 ? 63 : (t_);                                         \
      const ushort_t* src_ =                                                         \
          (G) + (size_t)((rowb) + (h_) * 128 + r0_ + srow) * KD + tc_ * 64 + csw;    \
      __builtin_amdgcn_global_load_lds(                                              \
          (const __attribute__((address_space(1))) u32*)src_,                        \
          (__attribute__((address_space(3))) u32*)&sbuf[s_][h_][r0_ * 64 + lane * 8],\
          16, 0, 0);                                                                 \
    }                                                                                \
  }
#define LGKM0                                          \
  asm volatile("s_waitcnt lgkmcnt(0)" ::: "memory");   \
  __builtin_amdgcn_sched_barrier(0)

  // ---- prologue: tile0 full + 3 half-tiles of tile1 in flight ----
  STG(sA, A, bm, 0, 0, 0); STG(sA, A, bm, 0, 0, 1);
  STG(sB, B, bn, 0, 0, 0); STG(sB, B, bn, 0, 0, 1);
  asm volatile("s_waitcnt vmcnt(4)" ::: "memory");
  STG(sA, A, bm, 1, 1, 0); STG(sA, A, bm, 1, 1, 1);
  STG(sB, B, bn, 1, 1, 1);
  asm volatile("s_waitcnt vmcnt(6)" ::: "memory");
  __builtin_amdgcn_s_barrier();

  bf16x8 af[4][2], b0[2][2], b1[2][2];

  for (int t = 0; t < 64; ++t) {
    const int s = t & 1;
    // ---- P1: quadrant (mh0,nh0); reads A-half0 + B-half0; stage B0(t+1) ----
#pragma unroll
    for (int mf = 0; mf < 4; ++mf)
#pragma unroll
      for (int kk = 0; kk < 2; ++kk)
        af[mf][kk] = *(const bf16x8*)
            &sA[s][0][(wm * 64 + mf * 16 + lq) * 64 + (((kk * 4 + g) ^ (lq & 7)) * 8)];
#pragma unroll
    for (int nf = 0; nf < 2; ++nf)
#pragma unroll
      for (int kk = 0; kk < 2; ++kk)
        b0[nf][kk] = *(const bf16x8*)
            &sB[s][0][(wn * 32 + nf * 16 + lq) * 64 + (((kk * 4 + g) ^ (lq & 7)) * 8)];
    STG(sB, B, bn, t + 1, s ^ 1, 0);
    __builtin_amdgcn_s_barrier();
    LGKM0;
    __builtin_amdgcn_s_setprio(1);
#pragma unroll
    for (int mf = 0; mf < 4; ++mf)
#pragma unroll
      for (int nf = 0; nf < 2; ++nf)
#pragma unroll
        for (int kk = 0; kk < 2; ++kk)
          acc[mf][nf] = __builtin_amdgcn_mfma_f32_16x16x32_bf16(af[mf][kk], b0[nf][kk],
                                                                acc[mf][nf], 0, 0, 0);
    __builtin_amdgcn_s_setprio(0);
    __builtin_amdgcn_s_barrier();
    // ---- P2: quadrant (mh0,nh1); reads B-half1 ----
#pragma unroll
    for (int nf = 0; nf < 2; ++nf)
#pragma unroll
      for (int kk = 0; kk < 2; ++kk)
        b1[nf][kk] = *(const bf16x8*)
            &sB[s][1][(wn * 32 + nf * 16 + lq) * 64 + (((kk * 4 + g) ^ (lq & 7)) * 8)];
    __builtin_amdgcn_s_barrier();
    LGKM0;
    __builtin_amdgcn_s_setprio(1);
#pragma unroll
    for (int mf = 0; mf < 4; ++mf)
#pragma unroll
      for (int nf = 0; nf < 2; ++nf)
#pragma unroll
        for (int kk = 0; kk < 2; ++kk)
          acc[mf][2 + nf] = __builtin_amdgcn_mfma_f32_16x16x32_bf16(af[mf][kk], b1[nf][kk],
                                                                    acc[mf][2 + nf], 0, 0, 0);
    __builtin_amdgcn_s_setprio(0);
    __builtin_amdgcn_s_barrier();
    // ---- P3: quadrant (mh1,nh1); reads A-half1; stage A0(t+2) ----
#pragma unroll
    for (int mf = 0; mf < 4; ++mf)
#pragma unroll
      for (int kk = 0; kk < 2; ++kk)
        af[mf][kk] = *(const bf16x8*)
            &sA[s][1][(wm * 64 + mf * 16 + lq) * 64 + (((kk * 4 + g) ^ (lq & 7)) * 8)];
    STG(sA, A, bm, t + 2, s, 0);
    __builtin_amdgcn_s_barrier();
    LGKM0;
    __builtin_amdgcn_s_setprio(1);
#pragma unroll
    for (int mf = 0; mf < 4; ++mf)
#pragma unroll
      for (int nf = 0; nf < 2; ++nf)
#pragma unroll
        for (int kk = 0; kk < 2; ++kk)
          acc[4 + mf][2 + nf] = __builtin_amdgcn_mfma_f32_16x16x32_bf16(
              af[mf][kk], b1[nf][kk], acc[4 + mf][2 + nf], 0, 0, 0);
    __builtin_amdgcn_s_setprio(0);
    __builtin_amdgcn_s_barrier();
    // ---- P4: quadrant (mh1,nh0); no reads (b0 held); stage A1(t+2),B1(t+2); vmcnt(6) ----
    STG(sA, A, bm, t + 2, s, 1);
    STG(sB, B, bn, t + 2, s, 1);
    __builtin_amdgcn_s_barrier();
    __builtin_amdgcn_s_setprio(1);
#pragma unroll
    for (int mf = 0; mf < 4; ++mf)
#pragma unroll
      for (int nf = 0; nf < 2; ++nf)
#pragma unroll
        for (int kk = 0; kk < 2; ++kk)
          acc[4 + mf][nf] = __builtin_amdgcn_mfma_f32_16x16x32_bf16(
              af[mf][kk], b0[nf][kk], acc[4 + mf][nf], 0, 0, 0);
    __builtin_amdgcn_s_setprio(0);
    asm volatile("s_waitcnt vmcnt(6)" ::: "memory");
    __builtin_amdgcn_s_barrier();
  }
#undef STG
#undef LGKM0

  // ---- epilogue: C store (C/D layout col=lane&15, row=(lane>>4)*4+reg) ----
#pragma unroll
  for (int m = 0; m < 8; ++m) {
    const int grow = bm + (m >> 2) * 128 + wm * 64 + (m & 3) * 16 + g * 4;
#pragma unroll
    for (int r = 0; r < 4; ++r)
#pragma unroll
      for (int n = 0; n < 4; ++n) {
        const int gcol = bn + (n >> 1) * 128 + wn * 32 + (n & 1) * 16 + lq;
        if (F32OUT)
          ((float*)C)[(size_t)(grow + r) * ND + gcol] = acc[m][n][r];
        else
          ((ushort_t*)C)[(size_t)(grow + r) * ND + gcol] = f2bf(acc[m][n][r]);
      }
  }
}

// ---------------- RoPE (in-place on bf16 Q and K); Q also gets 1/sqrt(128) ----------------
__global__ __launch_bounds__(256)
void rope_kernel(ushort_t* __restrict__ Q, ushort_t* __restrict__ K,
                 const float* __restrict__ fcos, const float* __restrict__ fsin) {
  const int gid = blockIdx.x * 256 + threadIdx.x;
  ushort_t* T = blockIdx.y ? K : Q;
  const float scale = blockIdx.y ? 1.f : 0.08838834764831845f;
  const int j8 = gid & 15;
  const int h = (gid >> 4) & 31;
  const int s = (gid >> 9) & 2047;
  const int b = gid >> 20;
  const size_t off = (size_t)(b * 2048 + s) * 4096 + h * 128 + j8 * 8;
  uint4 v = *(const uint4*)(T + off);
  const float4 c4 = *(const float4*)(fcos + s * 64 + j8 * 4);
  const float4 s4 = *(const float4*)(fsin + s * 64 + j8 * 4);
  u32 w[4] = {v.x, v.y, v.z, v.w};
  const float cc[4] = {c4.x, c4.y, c4.z, c4.w};
  const float ss[4] = {s4.x, s4.y, s4.z, s4.w};
#pragma unroll
  for (int p = 0; p < 4; ++p) {
    const float t0 = bf2f(w[p] & 0xffffu);
    const float t1 = bf2f(w[p] >> 16);
    const float r0 = (t0 * cc[p] - t1 * ss[p]) * scale;
    const float r1 = (t0 * ss[p] + t1 * cc[p]) * scale;
    w[p] = (u32)f2bf(r0) | ((u32)f2bf(r1) << 16);
  }
  v.x = w[0]; v.y = w[1]; v.z = w[2]; v.w = w[3];
  *(uint4*)(T + off) = v;
}

// ---------------- Flash attention, causal, 32x32 MFMA, folded-balance ----------------
__global__ __launch_bounds__(256, 2)
void attn_kernel(const ushort_t* __restrict__ Q, const ushort_t* __restrict__ K,
                 const ushort_t* __restrict__ Vt, ushort_t* __restrict__ O) {
  __shared__ ushort_t sK[2][32 * 128];   // swizzled col16 ^= row&7
  __shared__ ushort_t sV[2][128 * 32];   // swizzled slot ^= (d>>1)&3
  __shared__ float sScr[4][32];

  const int lane = threadIdx.x & 63, wave = threadIdx.x >> 6;
  const int lq = lane & 31, hi = lane >> 5;
  const int bp = blockIdx.x;
  const int bh = bp >> 3, j = bp & 7;
  const int h = bh & 31, b = bh >> 5;
  const ushort_t* Kb_ = K + (size_t)(b * 2048) * 4096 + h * 128;
  const ushort_t* Vb_ = Vt + (size_t)(h * 128) * 4096 + b * 2048;

#define STAGE(buf, kt_)                                                              \
  {                                                                                  \
    const int kb_ = (kt_) * 32;                                                      \
    _Pragma("unroll")                                                                \
    for (int i_ = 0; i_ < 2; ++i_) {                                                 \
      const int c_ = wave + i_ * 4;                                                  \
      const int krow = c_ * 4 + (lane >> 4);                                         \
      const int kcol = (lane & 15) ^ (krow & 7);                                     \
      const ushort_t* ksrc = Kb_ + (size_t)(kb_ + krow) * 4096 + kcol * 8;           \
      __builtin_amdgcn_global_load_lds(                                              \
          (const __attribute__((address_space(1))) u32*)ksrc,                        \
          (__attribute__((address_space(3))) u32*)&sK[buf][c_ * 512 + lane * 8],     \
          16, 0, 0);                                                                 \
      const int sst = c_ * 64 + lane;                                                \
      const int dv = sst >> 2;                                                       \
      const int gl = (sst & 3) ^ ((sst >> 3) & 3);                                   \
      const ushort_t* vsrc = Vb_ + (size_t)dv * 4096 + kb_ + gl * 8;                 \
      __builtin_amdgcn_global_load_lds(                                              \
          (const __attribute__((address_space(1))) u32*)vsrc,                        \
          (__attribute__((address_space(3))) u32*)&sV[buf][sst * 8], 16, 0, 0);      \
    }                                                                                \
  }

  for (int ph = 0; ph < 2; ++ph) {
    const int qj = ph ? (15 - j) : j;
    const int qbase = qj * 128 + wave * 32;
    const int ntw = qj * 4 + wave + 1;   // tiles this wave computes
    const int ntmax = qj * 4 + 4;        // tiles the block stages

    bf16x8 aq[8];
    const ushort_t* qrow = Q + (size_t)(b * 2048 + qbase + lq) * 4096 + h * 128 + hi * 8;
#pragma unroll
    for (int kf = 0; kf < 8; ++kf) aq[kf] = *(const bf16x8*)(qrow + kf * 16);

    f32x16 o[4];
#pragma unroll
    for (int dt = 0; dt < 4; ++dt) o[dt] = (f32x16)0.f;
    float m_run = -1e30f, l_run = 0.f;

    int cur = 0;
    STAGE(0, 0);
    __syncthreads();

    for (int kt = 0; kt < ntmax; ++kt) {
      if (kt + 1 < ntmax) STAGE(cur ^ 1, kt + 1);
      if (kt < ntw) {
        const int kb = kt * 32;
        f32x16 st = (f32x16)0.f;
#pragma unroll
        for (int kf = 0; kf < 8; ++kf) {
          const bf16x8 kfrag =
              *(const bf16x8*)&sK[cur][lq * 128 + (((kf * 2 + hi) ^ (lq & 7)) * 8)];
          st = __builtin_amdgcn_mfma_f32_32x32x16_bf16(kfrag, aq[kf], st, 0, 0, 0);
        }
        if (kt == ntw - 1) {
          const int q = qbase + lq;
#pragma unroll
          for (int r = 0; r < 16; ++r) {
            const int key = kb + (r & 3) + 8 * (r >> 2) + 4 * hi;
            if (key > q) st[r] = -1e30f;
          }
        }
        float tm = st[0];
#pragma unroll
        for (int r = 1; r < 16; ++r) tm = fmaxf(tm, st[r]);
        tm = fmaxf(tm, __shfl_xor(tm, 32));
        if (!__all(tm <= m_run + 8.f)) {   // T13 defer-max
          const float mnew = fmaxf(m_run, tm);
          const float corr = __expf(m_run - mnew);
          m_run = mnew;
          l_run *= corr;
          if (hi == 0) sScr[wave][lq] = corr;
          float fr[16];
#pragma unroll
          for (int r = 0; r < 16; ++r)
            fr[r] = sScr[wave][(r & 3) + 8 * (r >> 2) + 4 * hi];
#pragma unroll
          for (int dt = 0; dt < 4; ++dt)
#pragma unroll
            for (int r = 0; r < 16; ++r) o[dt][r] *= fr[r];
        }
        float rs = 0.f;
#pragma unroll
        for (int r = 0; r < 16; ++r) { st[r] = __expf(st[r] - m_run); rs += st[r]; }
        rs += __shfl_xor(rs, 32);
        l_run += rs;
        u32 A_, B_, C_, D_, E_, F_, G_, H_;
#define CVTPK(d_, l_, h_) \
  asm("v_cvt_pk_bf16_f32 %0, %1, %2" : "=v"(d_) : "v"(l_), "v"(h_))
        CVTPK(A_, st[0], st[1]);  CVTPK(B_, st[4], st[5]);
        CVTPK(C_, st[2], st[3]);  CVTPK(D_, st[6], st[7]);
        CVTPK(E_, st[8], st[9]);  CVTPK(F_, st[12], st[13]);
        CVTPK(G_, st[10], st[11]); CVTPK(H_, st[14], st[15]);
#undef CVTPK
        asm volatile("v_permlane32_swap_b32 %0, %1" : "+v"(A_), "+v"(B_));
        asm volatile("v_permlane32_swap_b32 %0, %1" : "+v"(C_), "+v"(D_));
        asm volatile("v_permlane32_swap_b32 %0, %1" : "+v"(E_), "+v"(F_));
        asm volatile("v_permlane32_swap_b32 %0, %1" : "+v"(G_), "+v"(H_));
        const bf16x8 pa0 = __builtin_bit_cast(bf16x8, (u32x4){A_, C_, B_, D_});
        const bf16x8 pa1 = __builtin_bit_cast(bf16x8, (u32x4){E_, G_, F_, H_});
#pragma unroll
        for (int dt = 0; dt < 4; ++dt) {
          const int d0 = dt * 32 + lq;
          const int s0 = 4 * d0 + ((hi + 0) ^ ((d0 >> 1) & 3));
          const int s1 = 4 * d0 + ((hi + 2) ^ ((d0 >> 1) & 3));
          const bf16x8 vf0 = *(const bf16x8*)&sV[cur][s0 * 8];
          const bf16x8 vf1 = *(const bf16x8*)&sV[cur][s1 * 8];
          o[dt] = __builtin_amdgcn_mfma_f32_32x32x16_bf16(pa0, vf0, o[dt], 0, 0, 0);
          o[dt] = __builtin_amdgcn_mfma_f32_32x32x16_bf16(pa1, vf1, o[dt], 0, 0, 0);
        }
      }
      __syncthreads();
      cur ^= 1;
    }

    if (hi == 0) sScr[wave][lq] = 1.f / l_run;
    __syncthreads();
    const size_t obase = (size_t)(b * 2048 + qbase) * 4096 + h * 128;
#pragma unroll
    for (int r = 0; r < 16; ++r) {
      const int qr = (r & 3) + 8 * (r >> 2) + 4 * hi;
      const float f = sScr[wave][qr];
#pragma unroll
      for (int dt = 0; dt < 4; ++dt)
        O[obase + (size_t)qr * 4096 + dt * 32 + lq] = f2bf(o[dt][r] * f);
    }
    __syncthreads();
  }
#undef STAGE
}

// ---------------- host ----------------
extern "C" void kernel_launch(void* const* d_in, const int* in_sizes, int n_in,
                              void* d_out, int out_size, void* d_ws, size_t ws_size,
                              hipStream_t stream) {
  const float* x = (const float*)d_in[0];
  const float* fcos = (const float*)d_in[2];
  const float* fsin = (const float*)d_in[3];
  const float* wq = (const float*)d_in[5];
  const float* wk = (const float*)d_in[6];
  const float* wv = (const float*)d_in[7];
  const float* wo = (const float*)d_in[8];
  float* out = (float*)d_out;
  char* ws = (char*)d_ws;
  const size_t MB32 = 33554432;  // 4096*4096*2 bytes
  ushort_t* xb = (ushort_t*)(ws);
  ushort_t* wb = (ushort_t*)(ws + MB32);
  ushort_t* Qb = (ushort_t*)(ws + 2 * MB32);
  ushort_t* Kb = (ushort_t*)(ws + 3 * MB32);
  ushort_t* Vt = (ushort_t*)(ws + 4 * MB32);
  ushort_t* Ob = xb;  // reuse: x no longer needed after V^T gemm

  const dim3 cb(256);
  const dim3 cg(8192);
  const dim3 gb(512);
  const dim3 gg(256);

  hipLaunchKernelGGL(cvt_kernel, cg, cb, 0, stream, x, xb);
  hipLaunchKernelGGL(cvt_kernel, cg, cb, 0, stream, wq, wb);
  hipLaunchKernelGGL((gemm256<0>), gg, gb, 0, stream, xb, wb, (void*)Qb);
  hipLaunchKernelGGL(cvt_kernel, cg, cb, 0, stream, wk, wb);
  hipLaunchKernelGGL((gemm256<0>), gg, gb, 0, stream, xb, wb, (void*)Kb);
  hipLaunchKernelGGL(cvt_kernel, cg, cb, 0, stream, wv, wb);
  hipLaunchKernelGGL((gemm256<0>), gg, gb, 0, stream, wb, xb, (void*)Vt);  // V^T = Wv @ x^T
  hipLaunchKernelGGL(rope_kernel, dim3(8192, 2), cb, 0, stream, Qb, Kb, fcos, fsin);
  hipLaunchKernelGGL(attn_kernel, dim3(512), cb, 0, stream, Qb, Kb, Vt, Ob);
  hipLaunchKernelGGL(cvt_kernel, cg, cb, 0, stream, wo, wb);
  hipLaunchKernelGGL((gemm256<1>), gg, gb, 0, stream, Ob, wb, (void*)out);
}

// Round 4
// 679.445 us; speedup vs baseline: 2.5544x; 1.0013x over previous
//
#include <hip/hip_runtime.h>

typedef unsigned short ushort_t;
typedef unsigned int u32;
typedef short bf16x8 __attribute__((ext_vector_type(8)));
typedef float f32x4 __attribute__((ext_vector_type(4)));
typedef float f32x16 __attribute__((ext_vector_type(16)));
typedef u32 u32x4 __attribute__((ext_vector_type(4)));

__device__ __forceinline__ ushort_t f2bf(float f) {
  u32 u = __builtin_bit_cast(u32, f);
  u += 0x7FFFu + ((u >> 16) & 1u);   // round-to-nearest-even
  return (ushort_t)(u >> 16);
}
__device__ __forceinline__ float bf2f(u32 bits16) {
  return __builtin_bit_cast(float, bits16 << 16);
}

// ---------------- fp32 -> bf16 convert (8 elems/thread) ----------------
__global__ __launch_bounds__(256)
void cvt_kernel(const float* __restrict__ in, ushort_t* __restrict__ out) {
  const int i = blockIdx.x * 256 + threadIdx.x;
  const float4 a = ((const float4*)in)[(size_t)i * 2];
  const float4 b = ((const float4*)in)[(size_t)i * 2 + 1];
  uint4 r;
  r.x = (u32)f2bf(a.x) | ((u32)f2bf(a.y) << 16);
  r.y = (u32)f2bf(a.z) | ((u32)f2bf(a.w) << 16);
  r.z = (u32)f2bf(b.x) | ((u32)f2bf(b.y) << 16);
  r.w = (u32)f2bf(b.z) | ((u32)f2bf(b.w) << 16);
  ((uint4*)out)[i] = r;
}

// ---------------- GEMM 256x256 8-phase: C[m][n] = sum_k A[m][k]*B[n][k] ----------------
// 512 threads = 8 waves (2M x 4N), BK=64. LDS 128 KiB (2 slots x 2 halves x
// 128x64 per tensor). T2 chunk^=(row&7) swizzle (inverse-swizzled global src,
// linear LDS dest, swizzled ds_read). 4 phases/K-tile, uniform {8,4,8,4}
// ds_reads per phase (B0-next register-double-buffered, read in P4 after the
// vmcnt(6) that drains it). Counted vmcnt(6) once per tile (T4), setprio (T5),
// 2-tile explicit unroll so all LDS bases are compile-time.
template <int F32OUT>
__global__ __launch_bounds__(512, 2)
void gemm256(const ushort_t* __restrict__ A, const ushort_t* __restrict__ B,
             void* __restrict__ C) {
  constexpr int KD = 4096, ND = 4096;
  __shared__ ushort_t sA[2][2][128 * 64];
  __shared__ ushort_t sB[2][2][128 * 64];
  const int tid = threadIdx.x;
  const int lane = tid & 63, wave = tid >> 6;
  const int lq = lane & 15, g = lane >> 4;
  const int wm = wave >> 2, wn = wave & 3;
  const int id = blockIdx.x;
  const int swz = (id & 7) * 32 + (id >> 3);       // bijective XCD swizzle (256%8==0)
  const int bm = (swz >> 4) * 256;
  const int bn = (swz & 15) * 256;
  const int csw = ((lane & 7) ^ (lane >> 3)) * 8;  // inverse-swizzled source chunk
  const int srow = lane >> 3;

  f32x4 acc[8][4];
#pragma unroll
  for (int m = 0; m < 8; ++m)
#pragma unroll
    for (int n = 0; n < 4; ++n) acc[m][n] = (f32x4)0.f;

#define STG(sbuf, G, rowb, t_, s_, h_)                                               \
  {                                                                                  \
    _Pragma("unroll") for (int i_ = 0; i_ < 2; ++i_) {                               \
      const int r0_ = wave * 16 + i_ * 8;                                            \
      const int tc_ = (t_) > 63 ? 63 : (t_);                                         \
      const ushort_t* src_ =                                                         \
          (G) + (size_t)((rowb) + (h_) * 128 + r0_ + srow) * KD + tc_ * 64 + csw;    \
      __builtin_amdgcn_global_load_lds(                                              \
          (const __attribute__((address_space(1))) u32*)src_,                        \
          (__attribute__((address_space(3))) u32*)&sbuf[s_][h_][r0_ * 64 + lane * 8],\
          16, 0, 0);                                                                 \
    }                                                                                \
  }
#define LGKM0                                          \
  asm volatile("s_waitcnt lgkmcnt(0)" ::: "memory");   \
  __builtin_amdgcn_sched_barrier(0)
#define RD_A(S_, H_, mf_, kk_)                                                        \
  (*(const bf16x8*)&sA[S_][H_][(wm * 64 + (mf_) * 16 + lq) * 64 +                     \
                               ((((kk_) * 4 + g) ^ (lq & 7)) * 8)])
#define RD_B(S_, H_, nf_, kk_)                                                        \
  (*(const bf16x8*)&sB[S_][H_][(wn * 32 + (nf_) * 16 + lq) * 64 +                     \
                               ((((kk_) * 4 + g) ^ (lq & 7)) * 8)])
#define MM(MB, NB, BR)                                                                \
  _Pragma("unroll") for (int mf = 0; mf < 4; ++mf)                                    \
    _Pragma("unroll") for (int nf = 0; nf < 2; ++nf)                                  \
      _Pragma("unroll") for (int kk = 0; kk < 2; ++kk)                                \
        acc[(MB) + mf][(NB) + nf] = __builtin_amdgcn_mfma_f32_16x16x32_bf16(          \
            af[mf][kk], BR[nf][kk], acc[(MB) + mf][(NB) + nf], 0, 0, 0)

  // ---- prologue: tile0 full + {A0,A1,B1} of tile1 in flight; preload b0c ----
  STG(sA, A, bm, 0, 0, 0); STG(sA, A, bm, 0, 0, 1);
  STG(sB, B, bn, 0, 0, 0); STG(sB, B, bn, 0, 0, 1);
  STG(sA, A, bm, 1, 1, 0); STG(sA, A, bm, 1, 1, 1);
  STG(sB, B, bn, 1, 1, 1);
  asm volatile("s_waitcnt vmcnt(6)" ::: "memory");   // drains tile0 (8 oldest)
  __builtin_amdgcn_s_barrier();

  bf16x8 af[4][2], b1[2][2], b0c[2][2], b0n[2][2];
#pragma unroll
  for (int nf = 0; nf < 2; ++nf)
#pragma unroll
    for (int kk = 0; kk < 2; ++kk) b0c[nf][kk] = RD_B(0, 0, nf, kk);

// One K-tile = 4 phases, uniform ds_reads {8,4,8,4}. B0C = this tile's B-half0
// regs (preloaded); B0N = next tile's, read in P4 after vmcnt(6) drains it.
#define TILE(S_, T_, B0C, B0N)                                                        \
  /* P1: read A0 (8); stage B0(t+1); MFMA Q(mh0,nh0) */                               \
  _Pragma("unroll") for (int mf = 0; mf < 4; ++mf)                                    \
    _Pragma("unroll") for (int kk = 0; kk < 2; ++kk)                                  \
      af[mf][kk] = RD_A(S_, 0, mf, kk);                                               \
  STG(sB, B, bn, (T_) + 1, (S_) ^ 1, 0);                                              \
  __builtin_amdgcn_s_barrier();                                                       \
  LGKM0;                                                                              \
  __builtin_amdgcn_s_setprio(1);                                                      \
  MM(0, 0, B0C);                                                                      \
  __builtin_amdgcn_s_setprio(0);                                                      \
  __builtin_amdgcn_s_barrier();                                                       \
  /* P2: read B1 (4); MFMA Q(mh0,nh1) */                                              \
  _Pragma("unroll") for (int nf = 0; nf < 2; ++nf)                                    \
    _Pragma("unroll") for (int kk = 0; kk < 2; ++kk)                                  \
      b1[nf][kk] = RD_B(S_, 1, nf, kk);                                               \
  __builtin_amdgcn_s_barrier();                                                       \
  LGKM0;                                                                              \
  __builtin_amdgcn_s_setprio(1);                                                      \
  MM(0, 2, b1);                                                                       \
  __builtin_amdgcn_s_setprio(0);                                                      \
  __builtin_amdgcn_s_barrier();                                                       \
  /* P3: read A1 (8); stage A0(t+2); MFMA Q(mh1,nh1) */                               \
  _Pragma("unroll") for (int mf = 0; mf < 4; ++mf)                                    \
    _Pragma("unroll") for (int kk = 0; kk < 2; ++kk)                                  \
      af[mf][kk] = RD_A(S_, 1, mf, kk);                                               \
  STG(sA, A, bm, (T_) + 2, S_, 0);                                                    \
  __builtin_amdgcn_s_barrier();                                                       \
  LGKM0;                                                                              \
  __builtin_amdgcn_s_setprio(1);                                                      \
  MM(4, 2, b1);                                                                       \
  __builtin_amdgcn_s_setprio(0);                                                      \
  __builtin_amdgcn_s_barrier();                                                       \
  /* P4: stage A1,B1(t+2); vmcnt(6) drains B0(t+1); MFMA Q(mh1,nh0); read B0N (4) */  \
  STG(sA, A, bm, (T_) + 2, S_, 1);                                                    \
  STG(sB, B, bn, (T_) + 2, S_, 1);                                                    \
  asm volatile("s_waitcnt vmcnt(6)" ::: "memory");                                    \
  __builtin_amdgcn_s_barrier();                                                       \
  LGKM0;                                                                              \
  __builtin_amdgcn_s_setprio(1);                                                      \
  MM(4, 0, B0C);                                                                      \
  __builtin_amdgcn_s_setprio(0);                                                      \
  _Pragma("unroll") for (int nf = 0; nf < 2; ++nf)                                    \
    _Pragma("unroll") for (int kk = 0; kk < 2; ++kk)                                  \
      B0N[nf][kk] = RD_B((S_) ^ 1, 0, nf, kk);                                        \
  __builtin_amdgcn_s_barrier();

  for (int t = 0; t < 64; t += 2) {
    TILE(0, t, b0c, b0n)
    TILE(1, t + 1, b0n, b0c)
  }
#undef TILE
#undef STG
#undef LGKM0
#undef RD_A
#undef RD_B
#undef MM

  // ---- epilogue: C store (C/D layout col=lane&15, row=(lane>>4)*4+reg) ----
#pragma unroll
  for (int m = 0; m < 8; ++m) {
    const int grow = bm + (m >> 2) * 128 + wm * 64 + (m & 3) * 16 + g * 4;
#pragma unroll
    for (int r = 0; r < 4; ++r)
#pragma unroll
      for (int n = 0; n < 4; ++n) {
        const int gcol = bn + (n >> 1) * 128 + wn * 32 + (n & 1) * 16 + lq;
        if (F32OUT)
          ((float*)C)[(size_t)(grow + r) * ND + gcol] = acc[m][n][r];
        else
          ((ushort_t*)C)[(size_t)(grow + r) * ND + gcol] = f2bf(acc[m][n][r]);
      }
  }
}

// ---------------- RoPE (in-place on bf16 Q and K); Q also gets 1/sqrt(128) ----------------
__global__ __launch_bounds__(256)
void rope_kernel(ushort_t* __restrict__ Q, ushort_t* __restrict__ K,
                 const float* __restrict__ fcos, const float* __restrict__ fsin) {
  const int gid = blockIdx.x * 256 + threadIdx.x;
  ushort_t* T = blockIdx.y ? K : Q;
  const float scale = blockIdx.y ? 1.f : 0.08838834764831845f;
  const int j8 = gid & 15;
  const int h = (gid >> 4) & 31;
  const int s = (gid >> 9) & 2047;
  const int b = gid >> 20;
  const size_t off = (size_t)(b * 2048 + s) * 4096 + h * 128 + j8 * 8;
  uint4 v = *(const uint4*)(T + off);
  const float4 c4 = *(const float4*)(fcos + s * 64 + j8 * 4);
  const float4 s4 = *(const float4*)(fsin + s * 64 + j8 * 4);
  u32 w[4] = {v.x, v.y, v.z, v.w};
  const float cc[4] = {c4.x, c4.y, c4.z, c4.w};
  const float ss[4] = {s4.x, s4.y, s4.z, s4.w};
#pragma unroll
  for (int p = 0; p < 4; ++p) {
    const float t0 = bf2f(w[p] & 0xffffu);
    const float t1 = bf2f(w[p] >> 16);
    const float r0 = (t0 * cc[p] - t1 * ss[p]) * scale;
    const float r1 = (t0 * ss[p] + t1 * cc[p]) * scale;
    w[p] = (u32)f2bf(r0) | ((u32)f2bf(r1) << 16);
  }
  v.x = w[0]; v.y = w[1]; v.z = w[2]; v.w = w[3];
  *(uint4*)(T + off) = v;
}

// ---------------- Flash attention, causal, 32x32 MFMA, folded-balance ----------------
__global__ __launch_bounds__(256, 2)
void attn_kernel(const ushort_t* __restrict__ Q, const ushort_t* __restrict__ K,
                 const ushort_t* __restrict__ Vt, ushort_t* __restrict__ O) {
  __shared__ ushort_t sK[2][32 * 128];   // swizzled col16 ^= row&7
  __shared__ ushort_t sV[2][128 * 32];   // swizzled slot ^= (d>>1)&3
  __shared__ float sScr[4][32];

  const int lane = threadIdx.x & 63, wave = threadIdx.x >> 6;
  const int lq = lane & 31, hi = lane >> 5;
  const int bp = blockIdx.x;
  const int bh = bp >> 3, j = bp & 7;
  const int h = bh & 31, b = bh >> 5;
  const ushort_t* Kb_ = K + (size_t)(b * 2048) * 4096 + h * 128;
  const ushort_t* Vb_ = Vt + (size_t)(h * 128) * 4096 + b * 2048;

#define STAGE(buf, kt_)                                                              \
  {                                                                                  \
    const int kb_ = (kt_) * 32;                                                      \
    _Pragma("unroll")                                                                \
    for (int i_ = 0; i_ < 2; ++i_) {                                                 \
      const int c_ = wave + i_ * 4;                                                  \
      const int krow = c_ * 4 + (lane >> 4);                                         \
      const int kcol = (lane & 15) ^ (krow & 7);                                     \
      const ushort_t* ksrc = Kb_ + (size_t)(kb_ + krow) * 4096 + kcol * 8;           \
      __builtin_amdgcn_global_load_lds(                                              \
          (const __attribute__((address_space(1))) u32*)ksrc,                        \
          (__attribute__((address_space(3))) u32*)&sK[buf][c_ * 512 + lane * 8],     \
          16, 0, 0);                                                                 \
      const int sst = c_ * 64 + lane;                                                \
      const int dv = sst >> 2;                                                       \
      const int gl = (sst & 3) ^ ((sst >> 3) & 3);                                   \
      const ushort_t* vsrc = Vb_ + (size_t)dv * 4096 + kb_ + gl * 8;                 \
      __builtin_amdgcn_global_load_lds(                                              \
          (const __attribute__((address_space(1))) u32*)vsrc,                        \
          (__attribute__((address_space(3))) u32*)&sV[buf][sst * 8], 16, 0, 0);      \
    }                                                                                \
  }

  for (int ph = 0; ph < 2; ++ph) {
    const int qj = ph ? (15 - j) : j;
    const int qbase = qj * 128 + wave * 32;
    const int ntw = qj * 4 + wave + 1;   // tiles this wave computes
    const int ntmax = qj * 4 + 4;        // tiles the block stages

    bf16x8 aq[8];
    const ushort_t* qrow = Q + (size_t)(b * 2048 + qbase + lq) * 4096 + h * 128 + hi * 8;
#pragma unroll
    for (int kf = 0; kf < 8; ++kf) aq[kf] = *(const bf16x8*)(qrow + kf * 16);

    f32x16 o[4];
#pragma unroll
    for (int dt = 0; dt < 4; ++dt) o[dt] = (f32x16)0.f;
    float m_run = -1e30f, l_run = 0.f;

    int cur = 0;
    STAGE(0, 0);
    __syncthreads();

    for (int kt = 0; kt < ntmax; ++kt) {
      if (kt + 1 < ntmax) STAGE(cur ^ 1, kt + 1);
      if (kt < ntw) {
        const int kb = kt * 32;
        f32x16 st = (f32x16)0.f;
#pragma unroll
        for (int kf = 0; kf < 8; ++kf) {
          const bf16x8 kfrag =
              *(const bf16x8*)&sK[cur][lq * 128 + (((kf * 2 + hi) ^ (lq & 7)) * 8)];
          st = __builtin_amdgcn_mfma_f32_32x32x16_bf16(kfrag, aq[kf], st, 0, 0, 0);
        }
        if (kt == ntw - 1) {
          const int q = qbase + lq;
#pragma unroll
          for (int r = 0; r < 16; ++r) {
            const int key = kb + (r & 3) + 8 * (r >> 2) + 4 * hi;
            if (key > q) st[r] = -1e30f;
          }
        }
        float tm = st[0];
#pragma unroll
        for (int r = 1; r < 16; ++r) tm = fmaxf(tm, st[r]);
        tm = fmaxf(tm, __shfl_xor(tm, 32));
        if (!__all(tm <= m_run + 8.f)) {   // T13 defer-max
          const float mnew = fmaxf(m_run, tm);
          const float corr = __expf(m_run - mnew);
          m_run = mnew;
          l_run *= corr;
          if (hi == 0) sScr[wave][lq] = corr;
          float fr[16];
#pragma unroll
          for (int r = 0; r < 16; ++r)
            fr[r] = sScr[wave][(r & 3) + 8 * (r >> 2) + 4 * hi];
#pragma unroll
          for (int dt = 0; dt < 4; ++dt)
#pragma unroll
            for (int r = 0; r < 16; ++r) o[dt][r] *= fr[r];
        }
        float rs = 0.f;
#pragma unroll
        for (int r = 0; r < 16; ++r) { st[r] = __expf(st[r] - m_run); rs += st[r]; }
        rs += __shfl_xor(rs, 32);
        l_run += rs;
        u32 A_, B_, C_, D_, E_, F_, G_, H_;
#define CVTPK(d_, l_, h_) \
  asm("v_cvt_pk_bf16_f32 %0, %1, %2" : "=v"(d_) : "v"(l_), "v"(h_))
        CVTPK(A_, st[0], st[1]);  CVTPK(B_, st[4], st[5]);
        CVTPK(C_, st[2], st[3]);  CVTPK(D_, st[6], st[7]);
        CVTPK(E_, st[8], st[9]);  CVTPK(F_, st[12], st[13]);
        CVTPK(G_, st[10], st[11]); CVTPK(H_, st[14], st[15]);
#undef CVTPK
        asm volatile("v_permlane32_swap_b32 %0, %1" : "+v"(A_), "+v"(B_));
        asm volatile("v_permlane32_swap_b32 %0, %1" : "+v"(C_), "+v"(D_));
        asm volatile("v_permlane32_swap_b32 %0, %1" : "+v"(E_), "+v"(F_));
        asm volatile("v_permlane32_swap_b32 %0, %1" : "+v"(G_), "+v"(H_));
        const bf16x8 pa0 = __builtin_bit_cast(bf16x8, (u32x4){A_, C_, B_, D_});
        const bf16x8 pa1 = __builtin_bit_cast(bf16x8, (u32x4){E_, G_, F_, H_});
#pragma unroll
        for (int dt = 0; dt < 4; ++dt) {
          const int d0 = dt * 32 + lq;
          const int s0 = 4 * d0 + ((hi + 0) ^ ((d0 >> 1) & 3));
          const int s1 = 4 * d0 + ((hi + 2) ^ ((d0 >> 1) & 3));
          const bf16x8 vf0 = *(const bf16x8*)&sV[cur][s0 * 8];
          const bf16x8 vf1 = *(const bf16x8*)&sV[cur][s1 * 8];
          o[dt] = __builtin_amdgcn_mfma_f32_32x32x16_bf16(pa0, vf0, o[dt], 0, 0, 0);
          o[dt] = __builtin_amdgcn_mfma_f32_32x32x16_bf16(pa1, vf1, o[dt], 0, 0, 0);
        }
      }
      __syncthreads();
      cur ^= 1;
    }

    if (hi == 0) sScr[wave][lq] = 1.f / l_run;
    __syncthreads();
    const size_t obase = (size_t)(b * 2048 + qbase) * 4096 + h * 128;
#pragma unroll
    for (int r = 0; r < 16; ++r) {
      const int qr = (r & 3) + 8 * (r >> 2) + 4 * hi;
      const float f = sScr[wave][qr];
#pragma unroll
      for (int dt = 0; dt < 4; ++dt)
        O[obase + (size_t)qr * 4096 + dt * 32 + lq] = f2bf(o[dt][r] * f);
    }
    __syncthreads();
  }
#undef STAGE
}

// ---------------- host ----------------
extern "C" void kernel_launch(void* const* d_in, const int* in_sizes, int n_in,
                              void* d_out, int out_size, void* d_ws, size_t ws_size,
                              hipStream_t stream) {
  const float* x = (const float*)d_in[0];
  const float* fcos = (const float*)d_in[2];
  const float* fsin = (const float*)d_in[3];
  const float* wq = (const float*)d_in[5];
  const float* wk = (const float*)d_in[6];
  const float* wv = (const float*)d_in[7];
  const float* wo = (const float*)d_in[8];
  float* out = (float*)d_out;
  char* ws = (char*)d_ws;
  const size_t MB32 = 33554432;  // 4096*4096*2 bytes
  ushort_t* xb = (ushort_t*)(ws);
  ushort_t* wb = (ushort_t*)(ws + MB32);
  ushort_t* Qb = (ushort_t*)(ws + 2 * MB32);
  ushort_t* Kb = (ushort_t*)(ws + 3 * MB32);
  ushort_t* Vt = (ushort_t*)(ws + 4 * MB32);
  ushort_t* Ob = xb;  // reuse: x no longer needed after V^T gemm

  const dim3 cb(256);
  const dim3 cg(8192);
  const dim3 gb(512);
  const dim3 gg(256);

  hipLaunchKernelGGL(cvt_kernel, cg, cb, 0, stream, x, xb);
  hipLaunchKernelGGL(cvt_kernel, cg, cb, 0, stream, wq, wb);
  hipLaunchKernelGGL((gemm256<0>), gg, gb, 0, stream, xb, wb, (void*)Qb);
  hipLaunchKernelGGL(cvt_kernel, cg, cb, 0, stream, wk, wb);
  hipLaunchKernelGGL((gemm256<0>), gg, gb, 0, stream, xb, wb, (void*)Kb);
  hipLaunchKernelGGL(cvt_kernel, cg, cb, 0, stream, wv, wb);
  hipLaunchKernelGGL((gemm256<0>), gg, gb, 0, stream, wb, xb, (void*)Vt);  // V^T = Wv @ x^T
  hipLaunchKernelGGL(rope_kernel, dim3(8192, 2), cb, 0, stream, Qb, Kb, fcos, fsin);
  hipLaunchKernelGGL(attn_kernel, dim3(512), cb, 0, stream, Qb, Kb, Vt, Ob);
  hipLaunchKernelGGL(cvt_kernel, cg, cb, 0, stream, wo, wb);
  hipLaunchKernelGGL((gemm256<1>), gg, gb, 0, stream, Ob, wb, (void*)out);
}